// Round 1
// baseline (1008.423 us; speedup 1.0000x reference)
//
#include <hip/hip_runtime.h>

#define C_CH 173
#define L_IN 400
#define EPSV 1e-5f
#define KFEAT 55360  // C*32*10

// ---------------------------------------------------------------------------
// Tower kernel: one block per (channel c, batch b). 320 threads = 5 waves.
// conv1(1->16,k9,p4) + BN + ReLU  ->  LDS y1[16][400+halo6]
// conv2(16->32,k7,p3) + BN + ReLU + maxpool(40) -> feat[b][ (c*32+f)*10 + p ]
// Block (0,0) additionally zeroes the h accumulator for the FC stage.
// ---------------------------------------------------------------------------
__global__ __launch_bounds__(320) void tower_kernel(
    const float* __restrict__ x,
    const float* __restrict__ w1, const float* __restrict__ b1,
    const float* __restrict__ g1, const float* __restrict__ beta1,
    const float* __restrict__ m1, const float* __restrict__ v1,
    const float* __restrict__ w2, const float* __restrict__ b2,
    const float* __restrict__ g2, const float* __restrict__ beta2,
    const float* __restrict__ m2, const float* __restrict__ v2,
    float* __restrict__ feat, float* __restrict__ h_ws)
{
    __shared__ float x_s[408];          // x with 4-halo each side
    __shared__ float w1_s[144];         // 16 x 9
    __shared__ float y1_s[16 * 408];    // 16 rows, 3-halo each side (406 used)
    __shared__ float w2_s[32 * 132];    // [f][g*8+dt], stride 132 -> banks f*4%32
    __shared__ float scale1_s[16], shift1_s[16], scale2_s[32], shift2_s[32];

    const int c   = blockIdx.x;
    const int b   = blockIdx.y;
    const int tid = threadIdx.x;

    if (c == 0 && b == 0) {
        for (int i = tid; i < 128 * 64; i += 320) h_ws[i] = 0.0f;
    }

    // ---- stage inputs ----
    const float* xrow = x + ((size_t)b * C_CH + c) * L_IN;
    for (int i = tid; i < 408; i += 320)
        x_s[i] = (i >= 4 && i < 404) ? xrow[i - 4] : 0.0f;

    for (int i = tid; i < 144; i += 320)
        w1_s[i] = w1[c * 144 + i];

    for (int i = tid; i < 32 * 112; i += 320) {
        int f = i / 112, r = i - f * 112;
        int g = r / 7,  dt = r - g * 7;
        w2_s[f * 132 + g * 8 + dt] = w2[(size_t)(c * 32 + f) * 112 + r];
    }

    // zero y1 halos (3 each side per row)
    if (tid < 96) {
        int g = tid / 6, j = tid - g * 6;
        int off = (j < 3) ? j : (400 + j);
        y1_s[g * 408 + off] = 0.0f;
    }

    // BN constants
    if (tid < 16) {
        int cf = c * 16 + tid;
        float inv = g1[cf] * rsqrtf(v1[cf] + EPSV);
        scale1_s[tid] = inv;
        shift1_s[tid] = (b1[cf] - m1[cf]) * inv + beta1[cf];
    }
    if (tid >= 64 && tid < 96) {
        int f = tid - 64;
        int cf = c * 32 + f;
        float inv = g2[cf] * rsqrtf(v2[cf] + EPSV);
        scale2_s[f] = inv;
        shift2_s[f] = (b2[cf] - m2[cf]) * inv + beta2[cf];
    }
    __syncthreads();

    // ---- conv1 + BN + ReLU -> y1_s ----
    for (int i = tid; i < 16 * 400; i += 320) {
        int g = i / 400;
        int t = i - g * 400;
        const float* wp = &w1_s[g * 9];
        float acc = 0.0f;
#pragma unroll
        for (int k = 0; k < 9; ++k) acc += wp[k] * x_s[t + k];
        float val = acc * scale1_s[g] + shift1_s[g];
        y1_s[g * 408 + t + 3] = val > 0.0f ? val : 0.0f;
    }
    __syncthreads();

    // ---- conv2 + BN + ReLU + maxpool(40) ----
    // thread -> (f, p): f = tid/10 in [0,32), p = tid%10 pool window
    const int f = tid / 10;
    const int p = tid - f * 10;

    float acc[5][8];
#pragma unroll
    for (int tc = 0; tc < 5; ++tc)
#pragma unroll
        for (int j = 0; j < 8; ++j) acc[tc][j] = 0.0f;

    for (int g = 0; g < 16; ++g) {
        float w[7];
#pragma unroll
        for (int dt = 0; dt < 7; ++dt) w[dt] = w2_s[f * 132 + g * 8 + dt];
#pragma unroll
        for (int tc = 0; tc < 5; ++tc) {
            const int base = g * 408 + p * 40 + tc * 8;  // y1_s idx == orig t-3 shift
            float xv[14];
#pragma unroll
            for (int i2 = 0; i2 < 14; ++i2) xv[i2] = y1_s[base + i2];
#pragma unroll
            for (int dt = 0; dt < 7; ++dt)
#pragma unroll
                for (int j = 0; j < 8; ++j)
                    acc[tc][j] += w[dt] * xv[j + dt];
        }
    }

    const float s2  = scale2_s[f];
    const float sh2 = shift2_s[f];
    float best = -1e30f;
#pragma unroll
    for (int tc = 0; tc < 5; ++tc)
#pragma unroll
        for (int j = 0; j < 8; ++j) {
            float v = acc[tc][j] * s2 + sh2;
            v = v > 0.0f ? v : 0.0f;
            best = v > best ? v : best;
        }

    feat[(size_t)b * KFEAT + (c * 32 + f) * 10 + p] = best;
}

// ---------------------------------------------------------------------------
// FC1 split-K: grid = 346 blocks, each handles KC=160 of K=55360.
// LDS-transposed feat tile (stride 161 -> (b+k)%32 banks, 2-way = free),
// wc1 rows read as wave-uniform float4 (scalar loads). atomicAdd partials.
// ---------------------------------------------------------------------------
__global__ __launch_bounds__(256) void fc1_kernel(
    const float* __restrict__ feat, const float* __restrict__ wc1,
    float* __restrict__ h_ws)
{
    __shared__ float fs[64 * 161];
    const int tid = threadIdx.x;
    const int k0  = blockIdx.x * 160;

    for (int idx = tid; idx < 64 * 40; idx += 256) {
        int b = idx / 40;
        int q = idx - b * 40;
        float4 v = *(const float4*)(feat + (size_t)b * KFEAT + k0 + q * 4);
        fs[b * 161 + q * 4 + 0] = v.x;
        fs[b * 161 + q * 4 + 1] = v.y;
        fs[b * 161 + q * 4 + 2] = v.z;
        fs[b * 161 + q * 4 + 3] = v.w;
    }
    __syncthreads();

    const int lane = tid & 63;                                   // = batch index
    const int wv   = __builtin_amdgcn_readfirstlane(tid >> 6);   // wave id 0..3

    for (int jg = 0; jg < 4; ++jg) {
        const int jbase = wv * 32 + jg * 8;
        float accs[8];
#pragma unroll
        for (int jj = 0; jj < 8; ++jj) accs[jj] = 0.0f;

        for (int q = 0; q < 40; ++q) {
            const float a0 = fs[lane * 161 + q * 4 + 0];
            const float a1 = fs[lane * 161 + q * 4 + 1];
            const float a2 = fs[lane * 161 + q * 4 + 2];
            const float a3 = fs[lane * 161 + q * 4 + 3];
#pragma unroll
            for (int jj = 0; jj < 8; ++jj) {
                const float4 w = *(const float4*)(wc1 + (size_t)(jbase + jj) * KFEAT + k0 + q * 4);
                accs[jj] += a0 * w.x + a1 * w.y + a2 * w.z + a3 * w.w;
            }
        }
#pragma unroll
        for (int jj = 0; jj < 8; ++jj)
            atomicAdd(&h_ws[(jbase + jj) * 64 + lane], accs[jj]);
    }
}

// ---------------------------------------------------------------------------
// FC2: out[b] = bc2 + sum_j wc2[j] * relu(h[j][b] + bc1[j])
// ---------------------------------------------------------------------------
__global__ __launch_bounds__(64) void fc2_kernel(
    const float* __restrict__ h_ws, const float* __restrict__ bc1,
    const float* __restrict__ wc2, const float* __restrict__ bc2,
    float* __restrict__ out)
{
    const int b = threadIdx.x;
    float acc = bc2[0];
    for (int j = 0; j < 128; ++j) {
        float hv = h_ws[j * 64 + b] + bc1[j];
        hv = hv > 0.0f ? hv : 0.0f;
        acc += wc2[j] * hv;
    }
    out[b] = acc;
}

extern "C" void kernel_launch(void* const* d_in, const int* in_sizes, int n_in,
                              void* d_out, int out_size, void* d_ws, size_t ws_size,
                              hipStream_t stream)
{
    const float* x     = (const float*)d_in[0];
    const float* w1    = (const float*)d_in[1];
    const float* b1    = (const float*)d_in[2];
    const float* g1    = (const float*)d_in[3];
    const float* beta1 = (const float*)d_in[4];
    const float* m1    = (const float*)d_in[5];
    const float* v1    = (const float*)d_in[6];
    const float* w2    = (const float*)d_in[7];
    const float* b2    = (const float*)d_in[8];
    const float* g2    = (const float*)d_in[9];
    const float* beta2 = (const float*)d_in[10];
    const float* m2    = (const float*)d_in[11];
    const float* v2    = (const float*)d_in[12];
    const float* wc1   = (const float*)d_in[13];
    const float* bc1   = (const float*)d_in[14];
    const float* wc2   = (const float*)d_in[15];
    const float* bc2   = (const float*)d_in[16];

    float* feat = (float*)d_ws;                                  // 64*55360 f32 = 14.17 MB
    float* h_ws = (float*)((char*)d_ws + (size_t)64 * KFEAT * 4); // 128*64 f32

    dim3 gtower(C_CH, 64);
    hipLaunchKernelGGL(tower_kernel, gtower, dim3(320), 0, stream,
                       x, w1, b1, g1, beta1, m1, v1,
                       w2, b2, g2, beta2, m2, v2, feat, h_ws);

    hipLaunchKernelGGL(fc1_kernel, dim3(346), dim3(256), 0, stream,
                       feat, wc1, h_ws);

    hipLaunchKernelGGL(fc2_kernel, dim3(1), dim3(64), 0, stream,
                       h_ws, bc1, wc2, bc2, (float*)d_out);
}

// Round 2
// 868.870 us; speedup vs baseline: 1.1606x; 1.1606x over previous
//
#include <hip/hip_runtime.h>

#define C_CH 173
#define L_IN 400
#define EPSV 1e-5f
#define KFEAT 55360  // C*32*10

// ---------------------------------------------------------------------------
// Tower kernel: one block per (channel c, batch b). 320 threads = 5 waves.
// conv1(1->16,k9,p4) + BN + ReLU  ->  LDS y1[16][400+halo6]
// conv2(16->32,k7,p3) + BN + ReLU + maxpool(40) -> feat[b][ (c*32+f)*10 + p ]
//
// conv2 thread map: f = tid&31, p = tid>>5.
//   - y1 reads: all lanes of a half-wave share (p) -> same-address broadcast
//     (free); the two half-waves differ by 40 floats -> different banks.
//   - w2 reads: stride 113 -> bank (f*17+r)%32, 17 coprime 32 -> permutation,
//     conflict-free. (R1 had 1.94e8 conflict cycles from the f/p map.)
// ---------------------------------------------------------------------------
__global__ __launch_bounds__(320) void tower_kernel(
    const float* __restrict__ x,
    const float* __restrict__ w1, const float* __restrict__ b1,
    const float* __restrict__ g1, const float* __restrict__ beta1,
    const float* __restrict__ m1, const float* __restrict__ v1,
    const float* __restrict__ w2, const float* __restrict__ b2,
    const float* __restrict__ g2, const float* __restrict__ beta2,
    const float* __restrict__ m2, const float* __restrict__ v2,
    float* __restrict__ feat, float* __restrict__ h_ws)
{
    __shared__ __align__(16) float x_s[408];        // x with 4-halo each side
    __shared__ float w1_s[144];                     // 16 x 9
    __shared__ __align__(16) float y1_s[16 * 408];  // 16 rows, 3-halo each side
    __shared__ float w2_s[32 * 113];                // [f][r], stride 113
    __shared__ float scale1_s[16], shift1_s[16], scale2_s[32], shift2_s[32];

    const int c   = blockIdx.x;
    const int b   = blockIdx.y;
    const int tid = threadIdx.x;

    if (c == 0 && b == 0) {
        for (int i = tid; i < 128 * 64; i += 320) h_ws[i] = 0.0f;
    }

    // ---- stage inputs ----
    const float* xrow = x + ((size_t)b * C_CH + c) * L_IN;
    for (int i = tid; i < 408; i += 320)
        x_s[i] = (i >= 4 && i < 404) ? xrow[i - 4] : 0.0f;

    for (int i = tid; i < 144; i += 320)
        w1_s[i] = w1[c * 144 + i];

    for (int i = tid; i < 32 * 112; i += 320) {
        int f = i / 112, r = i - f * 112;
        w2_s[f * 113 + r] = w2[(size_t)(c * 32 + f) * 112 + r];
    }

    // zero y1 halos (3 each side per row)
    if (tid < 96) {
        int g = tid / 6, j = tid - g * 6;
        int off = (j < 3) ? j : (400 + j);
        y1_s[g * 408 + off] = 0.0f;
    }

    // BN constants
    if (tid < 16) {
        int cf = c * 16 + tid;
        float inv = g1[cf] * rsqrtf(v1[cf] + EPSV);
        scale1_s[tid] = inv;
        shift1_s[tid] = (b1[cf] - m1[cf]) * inv + beta1[cf];
    }
    if (tid >= 64 && tid < 96) {
        int f = tid - 64;
        int cf = c * 32 + f;
        float inv = g2[cf] * rsqrtf(v2[cf] + EPSV);
        scale2_s[f] = inv;
        shift2_s[f] = (b2[cf] - m2[cf]) * inv + beta2[cf];
    }
    __syncthreads();

    // ---- conv1 + BN + ReLU -> y1_s ----
    for (int i = tid; i < 16 * 400; i += 320) {
        int g = i / 400;
        int t = i - g * 400;
        const float* wp = &w1_s[g * 9];
        float acc = 0.0f;
#pragma unroll
        for (int k = 0; k < 9; ++k) acc += wp[k] * x_s[t + k];
        float val = acc * scale1_s[g] + shift1_s[g];
        y1_s[g * 408 + t + 3] = val > 0.0f ? val : 0.0f;
    }
    __syncthreads();

    // ---- conv2 + BN + ReLU + maxpool(40) ----
    const int f = tid & 31;   // lane-variant -> w2 permutation banks
    const int p = tid >> 5;   // wave-uniform per half-wave -> y1 broadcast

    float acc[5][8];
#pragma unroll
    for (int tc = 0; tc < 5; ++tc)
#pragma unroll
        for (int j = 0; j < 8; ++j) acc[tc][j] = 0.0f;

    const float* wrow = &w2_s[f * 113];
    const float* yrow = &y1_s[p * 40];

    for (int g = 0; g < 16; ++g) {
        float w[7];
#pragma unroll
        for (int dt = 0; dt < 7; ++dt) w[dt] = wrow[g * 7 + dt];
        const float* yg = yrow + g * 408;
#pragma unroll
        for (int tc = 0; tc < 5; ++tc) {
            float xv[14];
            const float4 v0 = *(const float4*)(yg + tc * 8);
            const float4 v1 = *(const float4*)(yg + tc * 8 + 4);
            const float4 v2 = *(const float4*)(yg + tc * 8 + 8);
            const float2 v3 = *(const float2*)(yg + tc * 8 + 12);
            xv[0] = v0.x; xv[1] = v0.y; xv[2]  = v0.z; xv[3]  = v0.w;
            xv[4] = v1.x; xv[5] = v1.y; xv[6]  = v1.z; xv[7]  = v1.w;
            xv[8] = v2.x; xv[9] = v2.y; xv[10] = v2.z; xv[11] = v2.w;
            xv[12] = v3.x; xv[13] = v3.y;
#pragma unroll
            for (int dt = 0; dt < 7; ++dt)
#pragma unroll
                for (int j = 0; j < 8; ++j)
                    acc[tc][j] += w[dt] * xv[j + dt];
        }
    }

    const float s2  = scale2_s[f];
    const float sh2 = shift2_s[f];
    float best = -1e30f;
#pragma unroll
    for (int tc = 0; tc < 5; ++tc)
#pragma unroll
        for (int j = 0; j < 8; ++j) {
            float v = acc[tc][j] * s2 + sh2;
            v = v > 0.0f ? v : 0.0f;
            best = v > best ? v : best;
        }

    feat[(size_t)b * KFEAT + (c * 32 + f) * 10 + p] = best;
}

// ---------------------------------------------------------------------------
// FC1 split-K: grid = 346 blocks, each handles KC=160 of K=55360.
// LDS-transposed feat tile (stride 161), wc1 rows read as wave-uniform float4
// (scalar loads). atomicAdd partials.
// ---------------------------------------------------------------------------
__global__ __launch_bounds__(256) void fc1_kernel(
    const float* __restrict__ feat, const float* __restrict__ wc1,
    float* __restrict__ h_ws)
{
    __shared__ float fs[64 * 161];
    const int tid = threadIdx.x;
    const int k0  = blockIdx.x * 160;

    for (int idx = tid; idx < 64 * 40; idx += 256) {
        int b = idx / 40;
        int q = idx - b * 40;
        float4 v = *(const float4*)(feat + (size_t)b * KFEAT + k0 + q * 4);
        fs[b * 161 + q * 4 + 0] = v.x;
        fs[b * 161 + q * 4 + 1] = v.y;
        fs[b * 161 + q * 4 + 2] = v.z;
        fs[b * 161 + q * 4 + 3] = v.w;
    }
    __syncthreads();

    const int lane = tid & 63;                                   // = batch index
    const int wv   = __builtin_amdgcn_readfirstlane(tid >> 6);   // wave id 0..3

    for (int jg = 0; jg < 4; ++jg) {
        const int jbase = wv * 32 + jg * 8;
        float accs[8];
#pragma unroll
        for (int jj = 0; jj < 8; ++jj) accs[jj] = 0.0f;

        for (int q = 0; q < 40; ++q) {
            const float a0 = fs[lane * 161 + q * 4 + 0];
            const float a1 = fs[lane * 161 + q * 4 + 1];
            const float a2 = fs[lane * 161 + q * 4 + 2];
            const float a3 = fs[lane * 161 + q * 4 + 3];
#pragma unroll
            for (int jj = 0; jj < 8; ++jj) {
                const float4 w = *(const float4*)(wc1 + (size_t)(jbase + jj) * KFEAT + k0 + q * 4);
                accs[jj] += a0 * w.x + a1 * w.y + a2 * w.z + a3 * w.w;
            }
        }
#pragma unroll
        for (int jj = 0; jj < 8; ++jj)
            atomicAdd(&h_ws[(jbase + jj) * 64 + lane], accs[jj]);
    }
}

// ---------------------------------------------------------------------------
// FC2: out[b] = bc2 + sum_j wc2[j] * relu(h[j][b] + bc1[j])
// ---------------------------------------------------------------------------
__global__ __launch_bounds__(64) void fc2_kernel(
    const float* __restrict__ h_ws, const float* __restrict__ bc1,
    const float* __restrict__ wc2, const float* __restrict__ bc2,
    float* __restrict__ out)
{
    const int b = threadIdx.x;
    float acc = bc2[0];
    for (int j = 0; j < 128; ++j) {
        float hv = h_ws[j * 64 + b] + bc1[j];
        hv = hv > 0.0f ? hv : 0.0f;
        acc += wc2[j] * hv;
    }
    out[b] = acc;
}

extern "C" void kernel_launch(void* const* d_in, const int* in_sizes, int n_in,
                              void* d_out, int out_size, void* d_ws, size_t ws_size,
                              hipStream_t stream)
{
    const float* x     = (const float*)d_in[0];
    const float* w1    = (const float*)d_in[1];
    const float* b1    = (const float*)d_in[2];
    const float* g1    = (const float*)d_in[3];
    const float* beta1 = (const float*)d_in[4];
    const float* m1    = (const float*)d_in[5];
    const float* v1    = (const float*)d_in[6];
    const float* w2    = (const float*)d_in[7];
    const float* b2    = (const float*)d_in[8];
    const float* g2    = (const float*)d_in[9];
    const float* beta2 = (const float*)d_in[10];
    const float* m2    = (const float*)d_in[11];
    const float* v2    = (const float*)d_in[12];
    const float* wc1   = (const float*)d_in[13];
    const float* bc1   = (const float*)d_in[14];
    const float* wc2   = (const float*)d_in[15];
    const float* bc2   = (const float*)d_in[16];

    float* feat = (float*)d_ws;                                   // 64*55360 f32 = 14.17 MB
    float* h_ws = (float*)((char*)d_ws + (size_t)64 * KFEAT * 4); // 128*64 f32

    dim3 gtower(C_CH, 64);
    hipLaunchKernelGGL(tower_kernel, gtower, dim3(320), 0, stream,
                       x, w1, b1, g1, beta1, m1, v1,
                       w2, b2, g2, beta2, m2, v2, feat, h_ws);

    hipLaunchKernelGGL(fc1_kernel, dim3(346), dim3(256), 0, stream,
                       feat, wc1, h_ws);

    hipLaunchKernelGGL(fc2_kernel, dim3(1), dim3(64), 0, stream,
                       h_ws, bc1, wc2, bc2, (float*)d_out);
}

// Round 3
// 453.685 us; speedup vs baseline: 2.2227x; 1.9151x over previous
//
#include <hip/hip_runtime.h>

#define C_CH 173
#define L_IN 400
#define EPSV 1e-5f
#define KFEAT 55360  // C*32*10

typedef _Float16 f16x8 __attribute__((ext_vector_type(8)));
typedef float    f32x16 __attribute__((ext_vector_type(16)));

#define Y1T_STRIDE 34   // f16 elems per row = 17 dwords (odd -> bank permutation)
#define Y1T_ROWS   422  // t+dt in [0, 421]; row r == y1 time (r-3)
#define Y2_STRIDE  428  // f16 elems per row

// ---------------------------------------------------------------------------
// Tower kernel: one block per (channel c, batch b). 320 threads = 5 waves.
//  phase 1: stage x, w1, w2T(f16, [dt][f][g]), BN consts, zero y1T halo rows
//  phase 2: conv1(f32) + BN + ReLU -> y1T (f16, transposed [t][g])
//  phase 3: conv2 via 7x v_mfma_f32_32x32x16_f16 (K=16 per dt), BN+ReLU -> y2
//  phase 4: maxpool(40) as u16 integer max (monotone for ReLU'd f16) -> feat
// ---------------------------------------------------------------------------
__global__ __launch_bounds__(320) void tower_kernel(
    const float* __restrict__ x,
    const float* __restrict__ w1, const float* __restrict__ b1,
    const float* __restrict__ g1, const float* __restrict__ beta1,
    const float* __restrict__ m1, const float* __restrict__ v1,
    const float* __restrict__ w2, const float* __restrict__ b2,
    const float* __restrict__ g2, const float* __restrict__ beta2,
    const float* __restrict__ m2, const float* __restrict__ v2,
    float* __restrict__ feat, float* __restrict__ h_ws)
{
    __shared__ __align__(16) float    x_s[408];                 // 4-halo each side
    __shared__ float                  w1_s[144];                // 16 x 9
    __shared__ __align__(16) _Float16 y1T_s[Y1T_ROWS * Y1T_STRIDE];
    __shared__ __align__(16) _Float16 w2T_s[7 * 512];           // [dt][f][g]
    __shared__ __align__(16) _Float16 y2_s[32 * Y2_STRIDE];     // [f][t]
    __shared__ float scale1_s[16], shift1_s[16], scale2_s[32], shift2_s[32];

    const int c   = blockIdx.x;
    const int b   = blockIdx.y;
    const int tid = threadIdx.x;

    if (c == 0 && b == 0) {
        for (int i = tid; i < 128 * 64; i += 320) h_ws[i] = 0.0f;
    }

    // ---- phase 1: staging ----
    const float* xrow = x + ((size_t)b * C_CH + c) * L_IN;
    for (int i = tid; i < 408; i += 320)
        x_s[i] = (i >= 4 && i < 404) ? xrow[i - 4] : 0.0f;

    for (int i = tid; i < 144; i += 320)
        w1_s[i] = w1[c * 144 + i];

    // w2T[dt][f][g] as f16 (A-operand friendly: g contiguous)
    for (int i = tid; i < 3584; i += 320) {
        int f = i / 112, r = i - f * 112;
        int g = r / 7,  dt = r - g * 7;
        w2T_s[dt * 512 + f * 16 + g] = (_Float16)w2[(size_t)c * 3584 + i];
    }

    // zero y1T halo rows: rows 0..2 and 403..421 (22 rows x 17 dwords)
    if (tid < 22 * 17) {
        int r = tid / 17, cidx = tid - r * 17;
        int row = (r < 3) ? r : (400 + r);
        ((int*)y1T_s)[row * 17 + cidx] = 0;
    }

    if (tid < 16) {
        int cf = c * 16 + tid;
        float inv = g1[cf] * rsqrtf(v1[cf] + EPSV);
        scale1_s[tid] = inv;
        shift1_s[tid] = (b1[cf] - m1[cf]) * inv + beta1[cf];
    }
    if (tid >= 64 && tid < 96) {
        int f = tid - 64;
        int cf = c * 32 + f;
        float inv = g2[cf] * rsqrtf(v2[cf] + EPSV);
        scale2_s[f] = inv;
        shift2_s[f] = (b2[cf] - m2[cf]) * inv + beta2[cf];
    }
    __syncthreads();

    // ---- phase 2: conv1 + BN + ReLU -> y1T (transposed, f16) ----
    // i -> (g = i&15, t = i>>4): x_s read broadcast per 16-lane group,
    // w1_s stride-9 (9 coprime 32), y1T write 2-way max.
    for (int i = tid; i < 6400; i += 320) {
        int g = i & 15;
        int t = i >> 4;
        const float* wp = &w1_s[g * 9];
        float acc = 0.0f;
#pragma unroll
        for (int k = 0; k < 9; ++k) acc += wp[k] * x_s[t + k];
        float val = acc * scale1_s[g] + shift1_s[g];
        val = val > 0.0f ? val : 0.0f;
        y1T_s[(t + 3) * Y1T_STRIDE + g] = (_Float16)val;
    }
    __syncthreads();

    // ---- phase 3: conv2 = sum_dt W2dt[32x16] @ y1T-shift(dt) via MFMA ----
    {
        const int wv    = tid >> 6;        // wave 0..4
        const int lane  = tid & 63;
        const int nlane = lane & 31;       // n (=t in tile) for B/C; m (=f) for A
        const int half  = lane >> 5;       // k-half selector

        // A-frags: lane holds A[m=nlane][k=8*half+j] = w2T[dt][nlane][8*half+j]
        union { int4 q; f16x8 h; } af[7];
#pragma unroll
        for (int dt = 0; dt < 7; ++dt)
            af[dt].q = *(const int4*)((const int*)w2T_s + dt * 256 + nlane * 8 + half * 4);

        for (int tile = wv; tile < 13; tile += 5) {
            const int t0 = tile * 32 + nlane;
            f32x16 acc;
#pragma unroll
            for (int i = 0; i < 16; ++i) acc[i] = 0.0f;

#pragma unroll
            for (int dt = 0; dt < 7; ++dt) {
                // B[k=8*half+j][n=nlane] = y1T[t0+dt][8*half+j]
                const int* p = (const int*)y1T_s + (t0 + dt) * 17 + half * 4;
                union { int4 q; f16x8 h; } bf;
                bf.q.x = p[0]; bf.q.y = p[1]; bf.q.z = p[2]; bf.q.w = p[3];
                acc = __builtin_amdgcn_mfma_f32_32x32x16_f16(af[dt].h, bf.h, acc, 0, 0, 0);
            }

            // epilogue: BN + ReLU -> y2_s (f16)
#pragma unroll
            for (int reg = 0; reg < 16; ++reg) {
                int f = (reg & 3) + 8 * (reg >> 2) + 4 * half;
                float v = acc[reg] * scale2_s[f] + shift2_s[f];
                v = v > 0.0f ? v : 0.0f;
                y2_s[f * Y2_STRIDE + t0] = (_Float16)v;
            }
        }
    }
    __syncthreads();

    // ---- phase 4: maxpool(40) as u16 max (f16 >= 0 is u16-monotone) ----
    {
        const int f = tid & 31;
        const int p = tid >> 5;   // 0..9
        const unsigned long long* q =
            (const unsigned long long*)(y2_s + f * Y2_STRIDE + p * 40);
        unsigned mx = 0;
#pragma unroll
        for (int k = 0; k < 10; ++k) {
            unsigned long long v = q[k];
            unsigned a0 = (unsigned)(v & 0xFFFFu);
            unsigned a1 = (unsigned)((v >> 16) & 0xFFFFu);
            unsigned a2 = (unsigned)((v >> 32) & 0xFFFFu);
            unsigned a3 = (unsigned)(v >> 48);
            mx = mx > a0 ? mx : a0;
            mx = mx > a1 ? mx : a1;
            mx = mx > a2 ? mx : a2;
            mx = mx > a3 ? mx : a3;
        }
        union { unsigned short u; _Float16 h; } cv;
        cv.u = (unsigned short)mx;
        feat[(size_t)b * KFEAT + (c * 32 + f) * 10 + p] = (float)cv.h;
    }
}

// ---------------------------------------------------------------------------
// FC1 split-K: grid = 346 blocks, each handles KC=160 of K=55360.
// ---------------------------------------------------------------------------
__global__ __launch_bounds__(256) void fc1_kernel(
    const float* __restrict__ feat, const float* __restrict__ wc1,
    float* __restrict__ h_ws)
{
    __shared__ float fs[64 * 161];
    const int tid = threadIdx.x;
    const int k0  = blockIdx.x * 160;

    for (int idx = tid; idx < 64 * 40; idx += 256) {
        int b = idx / 40;
        int q = idx - b * 40;
        float4 v = *(const float4*)(feat + (size_t)b * KFEAT + k0 + q * 4);
        fs[b * 161 + q * 4 + 0] = v.x;
        fs[b * 161 + q * 4 + 1] = v.y;
        fs[b * 161 + q * 4 + 2] = v.z;
        fs[b * 161 + q * 4 + 3] = v.w;
    }
    __syncthreads();

    const int lane = tid & 63;                                   // = batch index
    const int wv   = __builtin_amdgcn_readfirstlane(tid >> 6);   // wave id 0..3

    for (int jg = 0; jg < 4; ++jg) {
        const int jbase = wv * 32 + jg * 8;
        float accs[8];
#pragma unroll
        for (int jj = 0; jj < 8; ++jj) accs[jj] = 0.0f;

        for (int q = 0; q < 40; ++q) {
            const float a0 = fs[lane * 161 + q * 4 + 0];
            const float a1 = fs[lane * 161 + q * 4 + 1];
            const float a2 = fs[lane * 161 + q * 4 + 2];
            const float a3 = fs[lane * 161 + q * 4 + 3];
#pragma unroll
            for (int jj = 0; jj < 8; ++jj) {
                const float4 w = *(const float4*)(wc1 + (size_t)(jbase + jj) * KFEAT + k0 + q * 4);
                accs[jj] += a0 * w.x + a1 * w.y + a2 * w.z + a3 * w.w;
            }
        }
#pragma unroll
        for (int jj = 0; jj < 8; ++jj)
            atomicAdd(&h_ws[(jbase + jj) * 64 + lane], accs[jj]);
    }
}

// ---------------------------------------------------------------------------
// FC2: out[b] = bc2 + sum_j wc2[j] * relu(h[j][b] + bc1[j])
// ---------------------------------------------------------------------------
__global__ __launch_bounds__(64) void fc2_kernel(
    const float* __restrict__ h_ws, const float* __restrict__ bc1,
    const float* __restrict__ wc2, const float* __restrict__ bc2,
    float* __restrict__ out)
{
    const int b = threadIdx.x;
    float acc = bc2[0];
    for (int j = 0; j < 128; ++j) {
        float hv = h_ws[j * 64 + b] + bc1[j];
        hv = hv > 0.0f ? hv : 0.0f;
        acc += wc2[j] * hv;
    }
    out[b] = acc;
}

extern "C" void kernel_launch(void* const* d_in, const int* in_sizes, int n_in,
                              void* d_out, int out_size, void* d_ws, size_t ws_size,
                              hipStream_t stream)
{
    const float* x     = (const float*)d_in[0];
    const float* w1    = (const float*)d_in[1];
    const float* b1    = (const float*)d_in[2];
    const float* g1    = (const float*)d_in[3];
    const float* beta1 = (const float*)d_in[4];
    const float* m1    = (const float*)d_in[5];
    const float* v1    = (const float*)d_in[6];
    const float* w2    = (const float*)d_in[7];
    const float* b2    = (const float*)d_in[8];
    const float* g2    = (const float*)d_in[9];
    const float* beta2 = (const float*)d_in[10];
    const float* m2    = (const float*)d_in[11];
    const float* v2    = (const float*)d_in[12];
    const float* wc1   = (const float*)d_in[13];
    const float* bc1   = (const float*)d_in[14];
    const float* wc2   = (const float*)d_in[15];
    const float* bc2   = (const float*)d_in[16];

    float* feat = (float*)d_ws;                                   // 64*55360 f32 = 14.17 MB
    float* h_ws = (float*)((char*)d_ws + (size_t)64 * KFEAT * 4); // 128*64 f32

    dim3 gtower(C_CH, 64);
    hipLaunchKernelGGL(tower_kernel, gtower, dim3(320), 0, stream,
                       x, w1, b1, g1, beta1, m1, v1,
                       w2, b2, g2, beta2, m2, v2, feat, h_ws);

    hipLaunchKernelGGL(fc1_kernel, dim3(346), dim3(256), 0, stream,
                       feat, wc1, h_ws);

    hipLaunchKernelGGL(fc2_kernel, dim3(1), dim3(64), 0, stream,
                       h_ws, bc1, wc2, bc2, (float*)d_out);
}

// Round 4
// 332.841 us; speedup vs baseline: 3.0297x; 1.3631x over previous
//
#include <hip/hip_runtime.h>

#define C_CH 173
#define L_IN 400
#define EPSV 1e-5f
#define KFEAT 55360  // C*32*10

typedef _Float16 f16x8  __attribute__((ext_vector_type(8)));
typedef float    f32x16 __attribute__((ext_vector_type(16)));

#define Y1T_STRIDE 36   // f16/row = 18 dwords: even (8B-aligned b64), gcd(18,32)=2 -> 2-way = free
#define Y1T_ROWS   422  // row r = y1 time (r-3); rows 0..2 and 403..421 zeroed

// 8-lane max via DPP (pure VALU, no DS pipe)
template <int CTRL>
__device__ __forceinline__ float dppf(float v) {
    int s = __builtin_bit_cast(int, v);
    int r = __builtin_amdgcn_update_dpp(0, s, CTRL, 0xF, 0xF, true);
    return __builtin_bit_cast(float, r);
}

// ---------------------------------------------------------------------------
// Tower kernel: one block per (channel c, batch b). 320 threads = 5 waves.
//  phase 1: stage x, w1, w2T(f16,[dt][f][g]), BN consts, zero y1T halos
//  phase 2: conv1(f32) + BN + ReLU -> y1T (f16, [t][g], stride 36)
//  phase 3: conv2 via 7x mfma_32x32x16_f16; BN+ReLU in regs; 8-wide DPP max
//           -> segmax[f][50] (t-segments of 8)
//  phase 4: pool = max of 5 segments -> feat (f16)
// LDS ~45.8 KB -> 3 blocks/CU (R3 was 64.5 KB -> 1 block/CU, the bottleneck)
// ---------------------------------------------------------------------------
__global__ __launch_bounds__(320) void tower_kernel(
    const float* __restrict__ x,
    const float* __restrict__ w1, const float* __restrict__ b1,
    const float* __restrict__ g1, const float* __restrict__ beta1,
    const float* __restrict__ m1, const float* __restrict__ v1,
    const float* __restrict__ w2, const float* __restrict__ b2,
    const float* __restrict__ g2, const float* __restrict__ beta2,
    const float* __restrict__ m2, const float* __restrict__ v2,
    _Float16* __restrict__ featH, float* __restrict__ h_ws)
{
    __shared__ __align__(16) float    x_s[408];
    __shared__ float                  w1_s[144];
    __shared__ __align__(16) _Float16 y1T_s[Y1T_ROWS * Y1T_STRIDE];
    __shared__ __align__(16) _Float16 w2T_s[7 * 512];        // [dt][f][g]
    __shared__ float                  segmax_s[32 * 53];     // [f][seg], stride 53
    __shared__ float scale1_s[16], shift1_s[16], scale2_s[32], shift2_s[32];

    const int c   = blockIdx.x;
    const int b   = blockIdx.y;
    const int tid = threadIdx.x;

    if (c == 0 && b == 0) {
        for (int i = tid; i < 128 * 64; i += 320) h_ws[i] = 0.0f;
    }

    // ---- phase 1: staging ----
    const float* xrow = x + ((size_t)b * C_CH + c) * L_IN;
    for (int i = tid; i < 408; i += 320)
        x_s[i] = (i >= 4 && i < 404) ? xrow[i - 4] : 0.0f;

    for (int i = tid; i < 144; i += 320)
        w1_s[i] = w1[c * 144 + i];

    // w2 via float4 (896 xfers), scatter to w2T[dt][f][g] f16
    for (int idx = tid; idx < 896; idx += 320) {
        float4 v = *(const float4*)(w2 + (size_t)c * 3584 + idx * 4);
        int i0 = idx * 4;
        int f = i0 / 112;
        int r = i0 - f * 112;
        float vv[4] = {v.x, v.y, v.z, v.w};
#pragma unroll
        for (int k = 0; k < 4; ++k) {
            int rr = r + k;                 // 112 % 4 == 0 -> same f
            int g = rr / 7, dt = rr - g * 7;
            w2T_s[dt * 512 + f * 16 + g] = (_Float16)vv[k];
        }
    }

    // zero y1T halo rows 0..2 and 403..421 (22 rows x 18 dwords)
    for (int i = tid; i < 22 * 18; i += 320) {
        int r = i / 18, cidx = i - r * 18;
        int row = (r < 3) ? r : (400 + r);
        ((int*)y1T_s)[row * 18 + cidx] = 0;
    }

    if (tid < 16) {
        int cf = c * 16 + tid;
        float inv = g1[cf] * rsqrtf(v1[cf] + EPSV);
        scale1_s[tid] = inv;
        shift1_s[tid] = (b1[cf] - m1[cf]) * inv + beta1[cf];
    }
    if (tid >= 64 && tid < 96) {
        int f = tid - 64;
        int cf = c * 32 + f;
        float inv = g2[cf] * rsqrtf(v2[cf] + EPSV);
        scale2_s[f] = inv;
        shift2_s[f] = (b2[cf] - m2[cf]) * inv + beta2[cf];
    }
    __syncthreads();

    // ---- phase 2: conv1 + BN + ReLU -> y1T ----
    for (int i = tid; i < 6400; i += 320) {
        int g = i & 15;
        int t = i >> 4;
        const float* wp = &w1_s[g * 9];
        float acc = 0.0f;
#pragma unroll
        for (int k = 0; k < 9; ++k) acc += wp[k] * x_s[t + k];
        float val = acc * scale1_s[g] + shift1_s[g];
        val = val > 0.0f ? val : 0.0f;
        y1T_s[(t + 3) * Y1T_STRIDE + g] = (_Float16)val;
    }
    __syncthreads();

    // ---- phase 3: conv2 MFMA + BN/ReLU + in-register 8-seg max ----
    {
        const int wv    = tid >> 6;
        const int lane  = tid & 63;
        const int nlane = lane & 31;
        const int half  = lane >> 5;

        union F8q { int4 q; f16x8 h; } af[7];
#pragma unroll
        for (int dt = 0; dt < 7; ++dt)
            af[dt].q = *(const int4*)((const int*)w2T_s + dt * 256 + nlane * 8 + half * 4);

        for (int tile = wv; tile < 13; tile += 5) {
            const int t0 = tile * 32 + nlane;
            f32x16 acc;
#pragma unroll
            for (int i = 0; i < 16; ++i) acc[i] = 0.0f;

#pragma unroll
            for (int dt = 0; dt < 7; ++dt) {
                const int* p = (const int*)y1T_s + (t0 + dt) * 18 + half * 4;
                union { int2 d[2]; f16x8 h; } bf;
                bf.d[0] = *(const int2*)p;
                bf.d[1] = *(const int2*)(p + 2);
                acc = __builtin_amdgcn_mfma_f32_32x32x16_f16(af[dt].h, bf.h, acc, 0, 0, 0);
            }

            const bool wr  = ((nlane & 7) == 0) && (t0 < 400);
            const int  seg = t0 >> 3;       // segment of 8 t-values
#pragma unroll
            for (int reg = 0; reg < 16; ++reg) {
                int f = (reg & 3) + 8 * (reg >> 2) + 4 * half;
                float v = acc[reg] * scale2_s[f] + shift2_s[f];
                v = fmaxf(v, 0.0f);
                v = fmaxf(v, dppf<0xB1>(v));    // xor 1 (quad_perm 1,0,3,2)
                v = fmaxf(v, dppf<0x4E>(v));    // xor 2 (quad_perm 2,3,0,1)
                v = fmaxf(v, dppf<0x141>(v));   // row_half_mirror (combine quads)
                if (wr) segmax_s[f * 53 + seg] = v;
            }
        }
    }
    __syncthreads();

    // ---- phase 4: pool(40) = max of 5 segment-maxes -> feat f16 ----
    {
        const int f = tid & 31;
        const int p = tid >> 5;
        float m = 0.0f;                      // post-ReLU values >= 0
#pragma unroll
        for (int k = 0; k < 5; ++k)
            m = fmaxf(m, segmax_s[f * 53 + p * 5 + k]);
        featH[(size_t)b * KFEAT + (c * 32 + f) * 10 + p] = (_Float16)m;
    }
}

// ---------------------------------------------------------------------------
// FC1 as f16 MFMA GEMM, split-K: 346 blocks x KC=160. M=128 (j), N=64 (b).
// Block: 256 threads = 4 waves; wave w owns j-tile w (32 rows), both N-tiles.
// LDS: wc1 slice f16 [128][164] (42 KB) + feat slice f16 [64][164] (21 KB).
// stride 164 f16 = 82 dwords: gcd(82,32)=2 -> 2-way (free), rows 8B-aligned.
// ---------------------------------------------------------------------------
__global__ __launch_bounds__(256) void fc1_kernel(
    const _Float16* __restrict__ featH, const float* __restrict__ wc1,
    float* __restrict__ h_ws)
{
    __shared__ _Float16 wT_s[128 * 164];
    __shared__ _Float16 fs_s[64 * 164];
    const int tid = threadIdx.x;
    const int k0  = blockIdx.x * 160;

    for (int idx = tid; idx < 5120; idx += 256) {
        int j = idx / 40, q = idx - j * 40;
        float4 v = *(const float4*)(wc1 + (size_t)j * KFEAT + k0 + q * 4);
        _Float16* d = &wT_s[j * 164 + q * 4];
        d[0] = (_Float16)v.x; d[1] = (_Float16)v.y;
        d[2] = (_Float16)v.z; d[3] = (_Float16)v.w;
    }
    for (int idx = tid; idx < 1280; idx += 256) {
        int bb = idx / 20, q = idx - bb * 20;
        int4 v = *(const int4*)(featH + (size_t)bb * KFEAT + k0 + q * 8);
        int* d = (int*)&fs_s[bb * 164 + q * 8];   // 8B-aligned (328*bb + 16*q)
        ((int2*)d)[0] = make_int2(v.x, v.y);
        ((int2*)d)[1] = make_int2(v.z, v.w);
    }
    __syncthreads();

    const int lane  = tid & 63;
    const int wv    = tid >> 6;      // j-tile
    const int nlane = lane & 31;
    const int half  = lane >> 5;

    f32x16 acc0, acc1;
#pragma unroll
    for (int i = 0; i < 16; ++i) { acc0[i] = 0.0f; acc1[i] = 0.0f; }

    const int arow = wv * 32 + nlane;
#pragma unroll 2
    for (int s = 0; s < 10; ++s) {
        union { int2 d[2]; f16x8 h; } a, b0, b1;
        const _Float16* ap  = &wT_s[arow * 164 + s * 16 + half * 8];
        a.d[0]  = *(const int2*)ap;       a.d[1]  = *(const int2*)(ap + 4);
        const _Float16* bp0 = &fs_s[nlane * 164 + s * 16 + half * 8];
        b0.d[0] = *(const int2*)bp0;      b0.d[1] = *(const int2*)(bp0 + 4);
        const _Float16* bp1 = &fs_s[(32 + nlane) * 164 + s * 16 + half * 8];
        b1.d[0] = *(const int2*)bp1;      b1.d[1] = *(const int2*)(bp1 + 4);
        acc0 = __builtin_amdgcn_mfma_f32_32x32x16_f16(a.h, b0.h, acc0, 0, 0, 0);
        acc1 = __builtin_amdgcn_mfma_f32_32x32x16_f16(a.h, b1.h, acc1, 0, 0, 0);
    }

#pragma unroll
    for (int reg = 0; reg < 16; ++reg) {
        int j = wv * 32 + (reg & 3) + 8 * (reg >> 2) + 4 * half;
        atomicAdd(&h_ws[j * 64 + nlane],      acc0[reg]);
        atomicAdd(&h_ws[j * 64 + 32 + nlane], acc1[reg]);
    }
}

// ---------------------------------------------------------------------------
// FC2: out[b] = bc2 + sum_j wc2[j] * relu(h[j][b] + bc1[j])
// ---------------------------------------------------------------------------
__global__ __launch_bounds__(64) void fc2_kernel(
    const float* __restrict__ h_ws, const float* __restrict__ bc1,
    const float* __restrict__ wc2, const float* __restrict__ bc2,
    float* __restrict__ out)
{
    const int b = threadIdx.x;
    float acc = bc2[0];
    for (int j = 0; j < 128; ++j) {
        float hv = h_ws[j * 64 + b] + bc1[j];
        hv = hv > 0.0f ? hv : 0.0f;
        acc += wc2[j] * hv;
    }
    out[b] = acc;
}

extern "C" void kernel_launch(void* const* d_in, const int* in_sizes, int n_in,
                              void* d_out, int out_size, void* d_ws, size_t ws_size,
                              hipStream_t stream)
{
    const float* x     = (const float*)d_in[0];
    const float* w1    = (const float*)d_in[1];
    const float* b1    = (const float*)d_in[2];
    const float* g1    = (const float*)d_in[3];
    const float* beta1 = (const float*)d_in[4];
    const float* m1    = (const float*)d_in[5];
    const float* v1    = (const float*)d_in[6];
    const float* w2    = (const float*)d_in[7];
    const float* b2    = (const float*)d_in[8];
    const float* g2    = (const float*)d_in[9];
    const float* beta2 = (const float*)d_in[10];
    const float* m2    = (const float*)d_in[11];
    const float* v2    = (const float*)d_in[12];
    const float* wc1   = (const float*)d_in[13];
    const float* bc1   = (const float*)d_in[14];
    const float* wc2   = (const float*)d_in[15];
    const float* bc2   = (const float*)d_in[16];

    _Float16* featH = (_Float16*)d_ws;                               // 64*55360 f16 = 7.09 MB
    float*    h_ws  = (float*)((char*)d_ws + (size_t)64 * KFEAT * 2); // 128*64 f32

    dim3 gtower(C_CH, 64);
    hipLaunchKernelGGL(tower_kernel, gtower, dim3(320), 0, stream,
                       x, w1, b1, g1, beta1, m1, v1,
                       w2, b2, g2, beta2, m2, v2, featH, h_ws);

    hipLaunchKernelGGL(fc1_kernel, dim3(346), dim3(256), 0, stream,
                       featH, wc1, h_ws);

    hipLaunchKernelGGL(fc2_kernel, dim3(1), dim3(64), 0, stream,
                       h_ws, bc1, wc2, bc2, (float*)d_out);
}